// Round 7
// baseline (6807.449 us; speedup 1.0000x reference)
//
#include <hip/hip_runtime.h>
#include <stdint.h>

typedef _Float16 half8 __attribute__((ext_vector_type(8)));
typedef _Float16 half4 __attribute__((ext_vector_type(4)));
typedef __attribute__((ext_vector_type(8))) short short8;
typedef __attribute__((ext_vector_type(4))) float f32x4;

// ---------- helpers ----------
__device__ __forceinline__ unsigned encf(float x){                // monotonic f32->u32
  uint32_t u = __float_as_uint(x);
  return (u & 0x80000000u) ? ~u : (u | 0x80000000u);
}
__device__ __forceinline__ float decf(unsigned u){
  uint32_t b = (u & 0x80000000u) ? (u & 0x7FFFFFFFu) : ~u;
  return __uint_as_float(b);
}
__device__ __forceinline__ void gload16(const void* g, void* l){
  __builtin_amdgcn_global_load_lds(
      (const __attribute__((address_space(1))) void*)g,
      (__attribute__((address_space(3))) void*)l, 16, 0, 0);
}

// ---------- small utility kernels ----------
__global__ __launch_bounds__(256) void zero_u32(unsigned* __restrict__ p, int n){
  for (int i = blockIdx.x*256 + threadIdx.x; i < n; i += gridDim.x*256) p[i] = 0u;
}

// w (f32, [CO][CI][3][3]) -> wp (fp16, [kc][tap][COP][32]) zero-padded, contiguous
// per-(kc,tap) 64B-per-co chunks for streaming a-frag loads.
__global__ __launch_bounds__(256) void pack_w(const float* __restrict__ w, _Float16* __restrict__ wp,
                                              int CO, int CI, int COP, int CINP){
  int idx = blockIdx.x*256 + threadIdx.x;
  int total = 9*COP*CINP;
  if (idx >= total) return;
  int ci = idx % CINP;
  int rest = idx / CINP;
  int co = rest % COP;
  int t  = rest / COP;
  float v = 0.f;
  if (co < CO && ci < CI) v = w[((size_t)co*CI + ci)*9 + t];
  int kc = ci >> 5, cr = ci & 31;
  wp[(((size_t)kc*9 + t)*COP + co)*32 + cr] = (_Float16)v;
}

__global__ __launch_bounds__(256) void pack_bias(const float* __restrict__ b, float* __restrict__ bp, int n, int npad){
  int i = blockIdx.x*256 + threadIdx.x;
  if (i < npad) bp[i] = (i < n) ? b[i] : 0.f;
}

// features f32 [16][36864] -> rnn_in (halo 194x194, interior at +1,+1) ch0..15
//                             k1_in (192x192) ch128..143
// if copy_state: k1_in ch0..127 (state) -> rnn_in ch16..143. batch = blockIdx.y.
__global__ __launch_bounds__(256) void pack_feat(const float* __restrict__ f,
                                                 _Float16* __restrict__ rnn_in,
                                                 _Float16* __restrict__ k1_in,
                                                 int copy_state,
                                                 unsigned fbstr, unsigned rbstr, unsigned kbstr){
  int p = blockIdx.x*256 + threadIdx.x;
  if (p >= 36864) return;
  int b = blockIdx.y;
  int y = p / 192, x = p % 192;
  const float* fb = f + (size_t)b*fbstr;
  _Float16* r = rnn_in + (size_t)b*rbstr + ((size_t)(y+1)*194 + (x+1))*160;
  _Float16* k = k1_in  + (size_t)b*kbstr + (size_t)p*160;
  #pragma unroll
  for (int c = 0; c < 16; ++c){
    _Float16 v = (_Float16)fb[c*36864 + p];
    r[c] = v;
    k[128 + c] = v;
  }
  if (copy_state){
    #pragma unroll
    for (int cc = 0; cc < 128; cc += 8)
      *reinterpret_cast<short8*>(r + 16 + cc) = *reinterpret_cast<const short8*>(k + cc);
  }
}

// ---------- conv3x3: LDS double-buffered fp16 implicit GEMM ----------
// block = 256 threads = 4 waves: wm = wid&1 (co half), wq = wid>>1 (row group).
// block tile: 128 co x NROW rows x 32 cols; wave tile: 64 co (C=4) x NROW/2 rows x 32 cols.
// NROW=4 for k3 (weight amortization); NROW=2 for the small convs (finer grid -> occupancy).
// Weights: packed [kc][tap][COP][32ch]; per-tap contiguous 4KB/wave stream (L1/L2-hot).
// Acts: LDS dbuf, per buffer [NROW+2 rows][4 sg][34 col][16B], staged via global_load_lds.
// All convs VALID-style (rnn uses zeroed halo buffer); OOB-ish reads land in
// allocation slack and only feed store-masked dead outputs.
template<int CINP, int NROW, bool RELU, bool K3>
__global__ __launch_bounds__(256, 6) void conv3(
    const _Float16* __restrict__ X, int Wst, unsigned xbstr,
    const _Float16* __restrict__ Wp, int COP,
    const float* __restrict__ bias,
    _Float16* __restrict__ Y, int Wst_out, int DCP, unsigned ybstr,
    unsigned* __restrict__ slot, int Ho, int Wo,
    int nco_mask, int nco_shift)
{
  constexpr int KC = CINP/32;
  constexpr int RPW = NROW/2;                 // rows per wave
  constexpr int SROWS = NROW + 2;             // staged act rows
  constexpr int ITEMS = SROWS*4*34;           // 16B items per buffer
  constexpr int NRND  = (ITEMS + 255)/256;    // stage rounds
  __shared__ _Float16 lds[2][ITEMS*8];

  const int tid  = threadIdx.x;
  const int lane = tid & 63;
  const int wid  = tid >> 6;
  const int wm   = wid & 1;
  const int wq   = wid >> 1;
  const int l15  = lane & 15, lg = lane >> 4;
  const int xb   = blockIdx.x * 32;
  const int yb   = blockIdx.y * NROW;
  const int co_blk = blockIdx.z & nco_mask;
  const int b      = blockIdx.z >> nco_shift;
  const int co_base = co_blk * 128;

  const _Float16* Xb = X + (size_t)b * xbstr;

  // stage addresses: ITEMS 16B items = [row SROWS][sg 4][col 34]
  uint32_t goff[NRND];
  #pragma unroll
  for (int k = 0; k < NRND; ++k){
    int item = k*256 + tid;
    if (item < ITEMS){
      int col = item % 34;
      int q   = item / 34;
      int sg  = q & 3;
      int row = q >> 2;
      int pix = (yb + row)*Wst + xb + col;
      goff[k] = (uint32_t)(((uint32_t)pix*CINP + sg*8) * 2);   // bytes
    } else goff[k] = 0;
  }

  auto stage = [&](int buf, int kc){
    const char* xp = (const char*)Xb + (size_t)kc*64;        // +32 channels
    char* lb = (char*)&lds[buf][0];
    #pragma unroll
    for (int k = 0; k < NRND; ++k){
      if (k*256 + tid < ITEMS)
        gload16(xp + goff[k], lb + k*4096 + wid*1024);
    }
  };

  // lane-constant b-frag element offsets (tap offset added as immediate):
  // elem(t,n) = boffe[n] + (ky*136 + kx)*8, with 136 = 4*34
  uint32_t boffe[NROW];
  #pragma unroll
  for (int n = 0; n < NROW; ++n){
    int nR = (NROW == 4) ? (n >> 1) : 0;
    int nC = (NROW == 4) ? (n & 1)  : n;
    boffe[n] = (uint32_t)((((wq*RPW + nR)*4 + lg)*34 + nC*16 + l15) * 8);
  }

  f32x4 acc[4][NROW] = {};
  // wave-lane weight base: co = co_base + wm*64 + l15, ch sub = lg*8
  const _Float16* wlane = Wp + ((size_t)(co_base + wm*64 + l15)*32 + lg*8);
  const size_t wtap = (size_t)COP*32;

  stage(0, 0);
  __syncthreads();
  for (int kc = 0; kc < KC; ++kc){
    if (kc + 1 < KC) stage((kc+1)&1, kc+1);
    const _Float16* wt = wlane + (size_t)kc*9*wtap;
    const _Float16* lb = &lds[kc&1][0];
    half8 wreg[2][4], breg[2][NROW];
    #pragma unroll
    for (int i = 0; i < 4; ++i)
      wreg[0][i] = *reinterpret_cast<const half8*>(wt + (size_t)i*512);
    #pragma unroll
    for (int n = 0; n < NROW; ++n)
      breg[0][n] = *reinterpret_cast<const half8*>(lb + boffe[n]);
    #pragma unroll
    for (int t = 0; t < 9; ++t){
      const int cur = t & 1, nxt = cur ^ 1;
      if (t < 8){
        const int ky = (t+1)/3, kx = (t+1) - ky*3;
        const _Float16* wn = wt + (size_t)(t+1)*wtap;
        #pragma unroll
        for (int i = 0; i < 4; ++i)
          wreg[nxt][i] = *reinterpret_cast<const half8*>(wn + (size_t)i*512);
        #pragma unroll
        for (int n = 0; n < NROW; ++n)
          breg[nxt][n] = *reinterpret_cast<const half8*>(lb + boffe[n] + (ky*136 + kx)*8);
      }
      #pragma unroll
      for (int n = 0; n < NROW; ++n)
        #pragma unroll
        for (int i = 0; i < 4; ++i)
          acc[i][n] = __builtin_amdgcn_mfma_f32_16x16x32_f16(wreg[cur][i], breg[cur][n], acc[i][n], 0, 0, 0);
    }
    if (kc + 1 < KC) __syncthreads();
  }

  // ---- epilogue ----
  float lmax = -3.0e38f;
  #pragma unroll
  for (int i = 0; i < 4; ++i){
    const int cb = co_base + wm*64 + i*16 + lg*4;   // 4 consecutive output channels
    f32x4 bs = *reinterpret_cast<const f32x4*>(bias + cb);
    #pragma unroll
    for (int n = 0; n < NROW; ++n){
      const int nR = (NROW == 4) ? (n >> 1) : 0;
      const int nC = (NROW == 4) ? (n & 1)  : n;
      const int y = yb + wq*RPW + nR;
      const int x = xb + nC*16 + l15;
      if (y < Ho && x < Wo){
        float v[4];
        #pragma unroll
        for (int j = 0; j < 4; ++j){
          float t = acc[i][n][j] + bs[j];
          if (RELU) t = t > 0.f ? t : 0.01f*t;
          v[j] = t;
        }
        if constexpr (!K3){
          half4 pk;
          #pragma unroll
          for (int j = 0; j < 4; ++j) pk[j] = (_Float16)v[j];
          *reinterpret_cast<half4*>(Y + (size_t)b*ybstr + ((size_t)y*Wst_out + x)*DCP + cb) = pk;
        } else {
          _Float16* yp = Y + (size_t)b*ybstr;
          #pragma unroll
          for (int j = 0; j < 4; ++j){
            if (cb + j < 441){
              yp[(size_t)(cb+j)*34596 + (size_t)y*186 + x] = (_Float16)v[j];
              lmax = fmaxf(lmax, v[j]);
            }
          }
        }
      }
    }
  }
  if constexpr (K3){
    #pragma unroll
    for (int o = 32; o > 0; o >>= 1) lmax = fmaxf(lmax, __shfl_xor(lmax, o));
    if (lane == 0) atomicMax(slot + b, encf(lmax));
  }
}

// streaming-max state update per batch: st[2b]=M, st[2b+1]=scale; resets slot
__global__ void update_max(float* __restrict__ st, unsigned* __restrict__ slot, int step){
  int b = threadIdx.x;
  if (b < 2){
    float nm   = decf(slot[b]);
    float oldM = st[2*b];
    float M    = (step == 0) ? nm : fmaxf(oldM, nm);
    st[2*b+1] = (step == 0) ? 0.f : expf(oldM - M);
    st[2*b]   = M;
    slot[b] = 0u;
  }
}

// per-pixel: w_t = exp(k3[t][y+7][x+7]-M); unnorm = unnorm*scale + sum_t w_t*rad
__global__ __launch_bounds__(256) void apply_acc(
    const _Float16* __restrict__ k3out, const float* __restrict__ rad,
    const float* __restrict__ st,
    float* __restrict__ unnorm, float* __restrict__ sumw)
{
  const int tx = threadIdx.x & 63, ty = threadIdx.x >> 6;
  const int x = blockIdx.x*64 + tx;
  const int y = blockIdx.y*4 + ty;
  const int b = blockIdx.z;
  if (x >= 172 || y >= 172) return;
  const float M = st[2*b], scale = st[2*b+1];
  const _Float16* kp = k3out + (size_t)b*15256836 + (size_t)(y+7)*186 + (x+7);
  const float* rb = rad + (size_t)b*884736;          // 8*3*36864
  float a0 = 0.f, a1 = 0.f, a2 = 0.f, aw = 0.f;
  for (int dy = 0; dy < 21; ++dy){
    const float* r0 = rb + (size_t)(y+dy)*192 + x;
    #pragma unroll
    for (int dx = 0; dx < 21; ++dx){
      float w = __expf((float)kp[(size_t)(dy*21+dx)*34596] - M);
      aw += w;
      a0 += w * r0[dx];
      a1 += w * r0[36864 + dx];
      a2 += w * r0[73728 + dx];
    }
  }
  size_t p = (size_t)b*88752 + (size_t)y*172 + x;
  size_t ps = (size_t)b*29584 + (size_t)y*172 + x;
  unnorm[p]        = unnorm[p]*scale        + a0;
  unnorm[p+29584]  = unnorm[p+29584]*scale  + a1;
  unnorm[p+59168]  = unnorm[p+59168]*scale  + a2;
  sumw[ps]         = sumw[ps]*scale         + aw;
}

__global__ __launch_bounds__(256) void finalize_out(const float* __restrict__ unnorm,
                                                    const float* __restrict__ sumw,
                                                    float* __restrict__ out){
  int i = blockIdx.x*256 + threadIdx.x;
  int b = blockIdx.y;
  if (i >= 88752) return;
  int p = i % 29584;
  out[(size_t)b*88752 + i] = unnorm[(size_t)b*88752 + i] / (sumw[(size_t)b*29584 + p] + 1e-8f);
}

// ---------- host ----------
extern "C" void kernel_launch(void* const* d_in, const int* in_sizes, int n_in,
                              void* d_out, int out_size, void* d_ws, size_t ws_size,
                              hipStream_t stream) {
  const float* features = (const float*)d_in[0];
  const float* radiance = (const float*)d_in[1];
  const float* w_rnn = (const float*)d_in[2];
  const float* b_rnn = (const float*)d_in[3];
  const float* w_k1  = (const float*)d_in[4];
  const float* b_k1  = (const float*)d_in[5];
  const float* w_k2  = (const float*)d_in[6];
  const float* b_k2  = (const float*)d_in[7];
  const float* w_k3  = (const float*)d_in[8];
  const float* b_k3  = (const float*)d_in[9];
  float* out = (float*)d_out;

  char* ws = (char*)d_ws;
  size_t off = 0;
  auto alloc = [&](size_t bytes)->char*{
    char* p = ws + off;
    off = (off + bytes + 255) & ~(size_t)255;
    return p;
  };
  _Float16* wp_rnn   = (_Float16*)alloc((size_t)9*128*160*2);
  _Float16* wp_k1    = (_Float16*)alloc((size_t)9*128*160*2);
  _Float16* wp_k2    = (_Float16*)alloc((size_t)9*128*128*2);
  _Float16* wp_k3    = (_Float16*)alloc((size_t)9*512*128*2);
  float*    bias_k3p = (float*)   alloc((size_t)512*4);
  // per-batch strides (elements)
  const unsigned RB = 194u*194u*160u;          // rnn_in
  const unsigned KB = (192u*192u+448u)*160u;   // k1_in
  const unsigned K2B = (190u*190u+444u)*128u;  // k2_in
  const unsigned K3B = (188u*188u+440u)*128u;  // k3_in
  const unsigned KOB = 441u*34596u;            // k3_out
  _Float16* rnn_in = (_Float16*)alloc((size_t)2*RB*2);
  _Float16* k1_in  = (_Float16*)alloc((size_t)2*KB*2);
  _Float16* k2_in  = (_Float16*)alloc((size_t)2*K2B*2);
  _Float16* k3_in  = (_Float16*)alloc((size_t)2*K3B*2);
  _Float16* k3_out = (_Float16*)alloc((size_t)2*KOB*2);
  float*    accz   = (float*)   alloc((size_t)236678*4);
  if (off > ws_size) return;  // workspace too small -> fail loudly (no OOB writes)

  float*    unnorm = accz;                 // [2][3][172][172]
  float*    sumw   = accz + 177504;        // [2][172][172]
  float*    st     = accz + 236672;        // [2][{M,scale}]
  unsigned* slot   = (unsigned*)(accz + 236676);  // [2]

  // weight prepack (pure function of inputs; runs every call)
  pack_w<<<(9*128*160+255)/256, 256, 0, stream>>>(w_rnn, wp_rnn, 128, 144, 128, 160);
  pack_w<<<(9*128*160+255)/256, 256, 0, stream>>>(w_k1,  wp_k1,  128, 144, 128, 160);
  pack_w<<<(9*128*128+255)/256, 256, 0, stream>>>(w_k2,  wp_k2,  128, 128, 128, 128);
  pack_w<<<(9*512*128+255)/256, 256, 0, stream>>>(w_k3,  wp_k3,  441, 128, 512, 128);
  pack_bias<<<2, 256, 0, stream>>>(b_k3, bias_k3p, 441, 512);

  // zero rnn halo+state (both batches) and accumulators
  zero_u32<<<2048, 256, 0, stream>>>((unsigned*)rnn_in, (int)(2*RB/2));
  zero_u32<<<925,  256, 0, stream>>>((unsigned*)accz, 236678);

  for (int s = 0; s < 8; ++s){
    const float* f   = features + (size_t)s*16*36864;   // batch stride 8*16*36864
    const float* rad = radiance + (size_t)s*3*36864;    // batch stride 8*3*36864
    pack_feat<<<dim3(144,2), 256, 0, stream>>>(f, rnn_in, k1_in, s > 0 ? 1 : 0,
                                               8u*16u*36864u, RB, KB);
    // rnn: 144(160)->128 SAME via zero halo, lrelu; -> k1_in ch0..127   (NROW=2)
    conv3<160,2,true ,false><<<dim3(6,96,2), 256, 0, stream>>>(
        rnn_in, 194, RB, wp_rnn, 128, b_rnn, k1_in, 192, 160, KB,
        nullptr, 192, 192, 0, 0);
    // k1: 144(160)->128 VALID, lrelu; -> k2_in (190x190)   (NROW=2)
    conv3<160,2,true ,false><<<dim3(6,95,2), 256, 0, stream>>>(
        k1_in, 192, KB, wp_k1, 128, b_k1, k2_in, 190, 128, K2B,
        nullptr, 190, 190, 0, 0);
    // k2: 128->128 VALID, lrelu; -> k3_in (188x188)   (NROW=2)
    conv3<128,2,true ,false><<<dim3(6,94,2), 256, 0, stream>>>(
        k2_in, 190, K2B, wp_k2, 128, b_k2, k3_in, 188, 128, K3B,
        nullptr, 188, 188, 0, 0);
    // k3: 128->441(512 pad, 4 slices) VALID, no relu; -> fp16 planes + atomic max (NROW=4)
    conv3<128,4,false,true ><<<dim3(6,47,8), 256, 0, stream>>>(
        k3_in, 188, K3B, wp_k3, 512, bias_k3p, k3_out, 0, 0, KOB,
        slot, 186, 186, 3, 2);
    update_max<<<1, 64, 0, stream>>>(st, slot, s);
    apply_acc<<<dim3(3,43,2), 256, 0, stream>>>(k3_out, rad, st, unnorm, sumw);
  }
  finalize_out<<<dim3(347,2), 256, 0, stream>>>(unnorm, sumw, out);
}

// Round 8
// 3449.759 us; speedup vs baseline: 1.9733x; 1.9733x over previous
//
#include <hip/hip_runtime.h>
#include <stdint.h>

typedef _Float16 half8 __attribute__((ext_vector_type(8)));
typedef _Float16 half4 __attribute__((ext_vector_type(4)));
typedef __attribute__((ext_vector_type(8))) short short8;
typedef __attribute__((ext_vector_type(4))) float f32x4;
typedef __attribute__((ext_vector_type(16))) float f32x16;

// ---------- helpers ----------
__device__ __forceinline__ unsigned encf(float x){                // monotonic f32->u32
  uint32_t u = __float_as_uint(x);
  return (u & 0x80000000u) ? ~u : (u | 0x80000000u);
}
__device__ __forceinline__ float decf(unsigned u){
  uint32_t b = (u & 0x80000000u) ? (u & 0x7FFFFFFFu) : ~u;
  return __uint_as_float(b);
}
__device__ __forceinline__ void gload16(const void* g, void* l){
  __builtin_amdgcn_global_load_lds(
      (const __attribute__((address_space(1))) void*)g,
      (__attribute__((address_space(3))) void*)l, 16, 0, 0);
}

// ---------- small utility kernels ----------
__global__ __launch_bounds__(256) void zero_u32(unsigned* __restrict__ p, int n){
  for (int i = blockIdx.x*256 + threadIdx.x; i < n; i += gridDim.x*256) p[i] = 0u;
}

// w (f32, [CO][CI][3][3]) -> wp (fp16, [kc16][tap][co_grp][32co x 16ch]) zero-padded.
// Per (kc,tap,grp) the 1KB region is exactly one wave a-frag: lane l reads 16B at
// (co&31)*32 + (l>>5)*16 bytes -> contiguous 1KB, elem (co,chl) at (co&31)*16+chl.
__global__ __launch_bounds__(256) void pack_w(const float* __restrict__ w, _Float16* __restrict__ wp,
                                              int CO, int CI, int COP, int CINP){
  int idx = blockIdx.x*256 + threadIdx.x;
  int total = 9*COP*CINP;
  if (idx >= total) return;
  int ci = idx % CINP;
  int rest = idx / CINP;
  int co = rest % COP;
  int t  = rest / COP;
  float v = 0.f;
  if (co < CO && ci < CI) v = w[((size_t)co*CI + ci)*9 + t];
  int kc = ci >> 4, chl = ci & 15;
  wp[(((size_t)kc*9 + t)*(COP/32) + (co>>5))*512 + (co&31)*16 + chl] = (_Float16)v;
}

__global__ __launch_bounds__(256) void pack_bias(const float* __restrict__ b, float* __restrict__ bp, int n, int npad){
  int i = blockIdx.x*256 + threadIdx.x;
  if (i < npad) bp[i] = (i < n) ? b[i] : 0.f;
}

// features f32 [16][36864] -> rnn_in (halo 194x194, interior at +1,+1) ch0..15
//                             k1_in (192x192) ch128..143
// if copy_state: k1_in ch0..127 (state) -> rnn_in ch16..143. batch = blockIdx.y.
__global__ __launch_bounds__(256) void pack_feat(const float* __restrict__ f,
                                                 _Float16* __restrict__ rnn_in,
                                                 _Float16* __restrict__ k1_in,
                                                 int copy_state,
                                                 unsigned fbstr, unsigned rbstr, unsigned kbstr){
  int p = blockIdx.x*256 + threadIdx.x;
  if (p >= 36864) return;
  int b = blockIdx.y;
  int y = p / 192, x = p % 192;
  const float* fb = f + (size_t)b*fbstr;
  _Float16* r = rnn_in + (size_t)b*rbstr + ((size_t)(y+1)*194 + (x+1))*160;
  _Float16* k = k1_in  + (size_t)b*kbstr + (size_t)p*160;
  #pragma unroll
  for (int c = 0; c < 16; ++c){
    _Float16 v = (_Float16)fb[c*36864 + p];
    r[c] = v;
    k[128 + c] = v;
  }
  if (copy_state){
    #pragma unroll
    for (int cc = 0; cc < 128; cc += 8)
      *reinterpret_cast<short8*>(r + 16 + cc) = *reinterpret_cast<const short8*>(k + cc);
  }
}

// ---------- conv3x3: 32x32x16-MFMA implicit GEMM, LDS double-buffered ----------
// block = 256 threads = 4 waves; wave wid owns output row yb+wid, 32 cols, 128 couts.
// Wave work per (kc16,tap): 1 ds_read_b128 (B: 32px x 16ch) feeds 4 MFMA (4 co-grps of 32)
//   -> LDS:MFMA = 12:32 cyc, 1.5x oversubscribed across 4 SIMDs (ceiling ~67% MfmaUtil).
// Weights: [kc16][tap][grp][32co x 16ch]; a-frag = contiguous 1KB/wave (L1/L2-hot).
// Acts: LDS dbuf [row6][col34][16ch] = 6528 B/buf, staged via global_load_lds (lane-linear).
// All convs VALID-style (rnn uses zeroed halo buffer); OOB-ish reads land in
// allocation slack and only feed store-masked dead outputs.
template<int CINP, bool RELU, bool K3>
__global__ __launch_bounds__(256, 3) void conv3(
    const _Float16* __restrict__ X, int Wst, unsigned xbstr,
    const _Float16* __restrict__ Wp, int COP,
    const float* __restrict__ bias,
    _Float16* __restrict__ Y, int Wst_out, int DCP, unsigned ybstr,
    unsigned* __restrict__ slot, int Ho, int Wo,
    int nco_mask, int nco_shift)
{
  constexpr int KC = CINP/16;
  __shared__ _Float16 lds[2][3264];          // 2 x 6528 B: [row6][col34][ch16]

  const int tid  = threadIdx.x;
  const int lane = tid & 63;
  const int wid  = tid >> 6;
  const int l31  = lane & 31;
  const int hsel = lane >> 5;
  const int xb   = blockIdx.x * 32;
  const int yb   = blockIdx.y * 4;
  const int co_blk = blockIdx.z & nco_mask;
  const int b      = blockIdx.z >> nco_shift;
  const int co_base = co_blk * 128;

  const _Float16* Xb = X + (size_t)b * xbstr;

  // stage addresses: 408 16B items = [row6][col34][half2]
  uint32_t goff[2];
  #pragma unroll
  for (int k = 0; k < 2; ++k){
    int item = k*256 + tid;
    if (item < 408){
      int row  = item / 68;
      int rem  = item % 68;
      int col  = rem >> 1;
      int half = rem & 1;
      int pix  = (yb + row)*Wst + xb + col;
      goff[k] = (uint32_t)(((uint32_t)pix*CINP + half*8) * 2);   // bytes
    } else goff[k] = 0;
  }

  auto stage = [&](int buf, int kc){
    const char* xp = (const char*)Xb + (size_t)kc*32;            // +16 channels
    char* lb = (char*)&lds[buf][0];
    gload16(xp + goff[0], lb + wid*1024);
    if (tid < 152)
      gload16(xp + goff[1], lb + 4096 + wid*1024);
  };

  // b-frag lane part: elem = (row*34 + col + l31)*16 + hsel*8
  const uint32_t blane = (uint32_t)(l31*16 + hsel*8);

  f32x16 acc[4] = {};
  // a-frag lane base: grp region 512 elems; lane elem = (co&31)*16 + (l>>5)*8
  const _Float16* wlane = Wp + ((size_t)co_blk*4)*512 + l31*16 + hsel*8;
  const int NG = COP/32;

  stage(0, 0);
  __syncthreads();
  for (int kc = 0; kc < KC; ++kc){
    if (kc + 1 < KC) stage((kc+1)&1, kc+1);
    const _Float16* wt = wlane + (size_t)(kc*9)*NG*512;
    const _Float16* lb = &lds[kc&1][0];
    half8 wreg[2][4], breg[2];
    #pragma unroll
    for (int g = 0; g < 4; ++g)
      wreg[0][g] = *reinterpret_cast<const half8*>(wt + g*512);
    breg[0] = *reinterpret_cast<const half8*>(lb + (wid*34)*16 + blane);
    #pragma unroll
    for (int t = 0; t < 9; ++t){
      const int cur = t & 1, nxt = cur ^ 1;
      if (t < 8){
        const int ky = (t+1)/3, kx = (t+1) - ky*3;
        const _Float16* wn = wt + (size_t)(t+1)*NG*512;
        #pragma unroll
        for (int g = 0; g < 4; ++g)
          wreg[nxt][g] = *reinterpret_cast<const half8*>(wn + g*512);
        breg[nxt] = *reinterpret_cast<const half8*>(lb + (((wid+ky)*34) + kx)*16 + blane);
      }
      #pragma unroll
      for (int g = 0; g < 4; ++g)
        acc[g] = __builtin_amdgcn_mfma_f32_32x32x16_f16(wreg[cur][g], breg[cur], acc[g], 0, 0, 0);
    }
    if (kc + 1 < KC) __syncthreads();
  }

  // ---- epilogue ----
  // C/D: px = xb + (lane&31); co = co_base + g*32 + 4*hsel + 8*q + j (reg = q*4+j)
  const int y = yb + wid;
  const int x = xb + l31;
  float lmax = -3.0e38f;
  if (y < Ho && x < Wo){
    #pragma unroll
    for (int g = 0; g < 4; ++g){
      #pragma unroll
      for (int q = 0; q < 4; ++q){
        const int cb = co_base + g*32 + 4*hsel + 8*q;   // 4 consecutive couts
        f32x4 bs = *reinterpret_cast<const f32x4*>(bias + cb);
        float v[4];
        #pragma unroll
        for (int j = 0; j < 4; ++j){
          float tv = acc[g][q*4 + j] + bs[j];
          if (RELU) tv = tv > 0.f ? tv : 0.01f*tv;
          v[j] = tv;
        }
        if constexpr (!K3){
          half4 pk;
          #pragma unroll
          for (int j = 0; j < 4; ++j) pk[j] = (_Float16)v[j];
          *reinterpret_cast<half4*>(Y + (size_t)b*ybstr + ((size_t)y*Wst_out + x)*DCP + cb) = pk;
        } else {
          _Float16* yp = Y + (size_t)b*ybstr;
          #pragma unroll
          for (int j = 0; j < 4; ++j){
            if (cb + j < 441){
              yp[(size_t)(cb+j)*34596 + (size_t)y*186 + x] = (_Float16)v[j];
              lmax = fmaxf(lmax, v[j]);
            }
          }
        }
      }
    }
  }
  if constexpr (K3){
    #pragma unroll
    for (int o = 32; o > 0; o >>= 1) lmax = fmaxf(lmax, __shfl_xor(lmax, o));
    if (lane == 0) atomicMax(slot + b, encf(lmax));
  }
}

// streaming-max state update per batch: st[2b]=M, st[2b+1]=scale; resets slot
__global__ void update_max(float* __restrict__ st, unsigned* __restrict__ slot, int step){
  int b = threadIdx.x;
  if (b < 2){
    float nm   = decf(slot[b]);
    float oldM = st[2*b];
    float M    = (step == 0) ? nm : fmaxf(oldM, nm);
    st[2*b+1] = (step == 0) ? 0.f : expf(oldM - M);
    st[2*b]   = M;
    slot[b] = 0u;
  }
}

// per-pixel: w_t = exp(k3[t][y+7][x+7]-M); unnorm = unnorm*scale + sum_t w_t*rad
__global__ __launch_bounds__(256) void apply_acc(
    const _Float16* __restrict__ k3out, const float* __restrict__ rad,
    const float* __restrict__ st,
    float* __restrict__ unnorm, float* __restrict__ sumw)
{
  const int tx = threadIdx.x & 63, ty = threadIdx.x >> 6;
  const int x = blockIdx.x*64 + tx;
  const int y = blockIdx.y*4 + ty;
  const int b = blockIdx.z;
  if (x >= 172 || y >= 172) return;
  const float M = st[2*b], scale = st[2*b+1];
  const _Float16* kp = k3out + (size_t)b*15256836 + (size_t)(y+7)*186 + (x+7);
  const float* rb = rad + (size_t)b*884736;          // 8*3*36864
  float a0 = 0.f, a1 = 0.f, a2 = 0.f, aw = 0.f;
  for (int dy = 0; dy < 21; ++dy){
    const float* r0 = rb + (size_t)(y+dy)*192 + x;
    #pragma unroll
    for (int dx = 0; dx < 21; ++dx){
      float w = __expf((float)kp[(size_t)(dy*21+dx)*34596] - M);
      aw += w;
      a0 += w * r0[dx];
      a1 += w * r0[36864 + dx];
      a2 += w * r0[73728 + dx];
    }
  }
  size_t p = (size_t)b*88752 + (size_t)y*172 + x;
  size_t ps = (size_t)b*29584 + (size_t)y*172 + x;
  unnorm[p]        = unnorm[p]*scale        + a0;
  unnorm[p+29584]  = unnorm[p+29584]*scale  + a1;
  unnorm[p+59168]  = unnorm[p+59168]*scale  + a2;
  sumw[ps]         = sumw[ps]*scale         + aw;
}

__global__ __launch_bounds__(256) void finalize_out(const float* __restrict__ unnorm,
                                                    const float* __restrict__ sumw,
                                                    float* __restrict__ out){
  int i = blockIdx.x*256 + threadIdx.x;
  int b = blockIdx.y;
  if (i >= 88752) return;
  int p = i % 29584;
  out[(size_t)b*88752 + i] = unnorm[(size_t)b*88752 + i] / (sumw[(size_t)b*29584 + p] + 1e-8f);
}

// ---------- host ----------
extern "C" void kernel_launch(void* const* d_in, const int* in_sizes, int n_in,
                              void* d_out, int out_size, void* d_ws, size_t ws_size,
                              hipStream_t stream) {
  const float* features = (const float*)d_in[0];
  const float* radiance = (const float*)d_in[1];
  const float* w_rnn = (const float*)d_in[2];
  const float* b_rnn = (const float*)d_in[3];
  const float* w_k1  = (const float*)d_in[4];
  const float* b_k1  = (const float*)d_in[5];
  const float* w_k2  = (const float*)d_in[6];
  const float* b_k2  = (const float*)d_in[7];
  const float* w_k3  = (const float*)d_in[8];
  const float* b_k3  = (const float*)d_in[9];
  float* out = (float*)d_out;

  char* ws = (char*)d_ws;
  size_t off = 0;
  auto alloc = [&](size_t bytes)->char*{
    char* p = ws + off;
    off = (off + bytes + 255) & ~(size_t)255;
    return p;
  };
  _Float16* wp_rnn   = (_Float16*)alloc((size_t)9*128*160*2);
  _Float16* wp_k1    = (_Float16*)alloc((size_t)9*128*160*2);
  _Float16* wp_k2    = (_Float16*)alloc((size_t)9*128*128*2);
  _Float16* wp_k3    = (_Float16*)alloc((size_t)9*512*128*2);
  float*    bias_k3p = (float*)   alloc((size_t)512*4);
  // per-batch strides (elements)
  const unsigned RB = 194u*194u*160u;          // rnn_in
  const unsigned KB = (192u*192u+448u)*160u;   // k1_in
  const unsigned K2B = (190u*190u+444u)*128u;  // k2_in
  const unsigned K3B = (188u*188u+440u)*128u;  // k3_in
  const unsigned KOB = 441u*34596u;            // k3_out
  _Float16* rnn_in = (_Float16*)alloc((size_t)2*RB*2);
  _Float16* k1_in  = (_Float16*)alloc((size_t)2*KB*2);
  _Float16* k2_in  = (_Float16*)alloc((size_t)2*K2B*2);
  _Float16* k3_in  = (_Float16*)alloc((size_t)2*K3B*2);
  _Float16* k3_out = (_Float16*)alloc((size_t)2*KOB*2);
  float*    accz   = (float*)   alloc((size_t)236678*4);
  if (off > ws_size) return;  // workspace too small -> fail loudly (no OOB writes)

  float*    unnorm = accz;                 // [2][3][172][172]
  float*    sumw   = accz + 177504;        // [2][172][172]
  float*    st     = accz + 236672;        // [2][{M,scale}]
  unsigned* slot   = (unsigned*)(accz + 236676);  // [2]

  // weight prepack (pure function of inputs; runs every call)
  pack_w<<<(9*128*160+255)/256, 256, 0, stream>>>(w_rnn, wp_rnn, 128, 144, 128, 160);
  pack_w<<<(9*128*160+255)/256, 256, 0, stream>>>(w_k1,  wp_k1,  128, 144, 128, 160);
  pack_w<<<(9*128*128+255)/256, 256, 0, stream>>>(w_k2,  wp_k2,  128, 128, 128, 128);
  pack_w<<<(9*512*128+255)/256, 256, 0, stream>>>(w_k3,  wp_k3,  441, 128, 512, 128);
  pack_bias<<<2, 256, 0, stream>>>(b_k3, bias_k3p, 441, 512);

  // zero rnn halo+state (both batches) and accumulators
  zero_u32<<<2048, 256, 0, stream>>>((unsigned*)rnn_in, (int)(2*RB/2));
  zero_u32<<<925,  256, 0, stream>>>((unsigned*)accz, 236678);

  for (int s = 0; s < 8; ++s){
    const float* f   = features + (size_t)s*16*36864;   // batch stride 8*16*36864
    const float* rad = radiance + (size_t)s*3*36864;    // batch stride 8*3*36864
    pack_feat<<<dim3(144,2), 256, 0, stream>>>(f, rnn_in, k1_in, s > 0 ? 1 : 0,
                                               8u*16u*36864u, RB, KB);
    // rnn: 144(160)->128 SAME via zero halo, lrelu; -> k1_in ch0..127
    conv3<160,true ,false><<<dim3(6,48,2), 256, 0, stream>>>(
        rnn_in, 194, RB, wp_rnn, 128, b_rnn, k1_in, 192, 160, KB,
        nullptr, 192, 192, 0, 0);
    // k1: 144(160)->128 VALID, lrelu; -> k2_in (190x190)
    conv3<160,true ,false><<<dim3(6,48,2), 256, 0, stream>>>(
        k1_in, 192, KB, wp_k1, 128, b_k1, k2_in, 190, 128, K2B,
        nullptr, 190, 190, 0, 0);
    // k2: 128->128 VALID, lrelu; -> k3_in (188x188)
    conv3<128,true ,false><<<dim3(6,47,2), 256, 0, stream>>>(
        k2_in, 190, K2B, wp_k2, 128, b_k2, k3_in, 188, 128, K3B,
        nullptr, 188, 188, 0, 0);
    // k3: 128->441(512 pad, 4 slices) VALID, no relu; -> fp16 planes + atomic max
    conv3<128,false,true ><<<dim3(6,47,8), 256, 0, stream>>>(
        k3_in, 188, K3B, wp_k3, 512, bias_k3p, k3_out, 0, 0, KOB,
        slot, 186, 186, 3, 2);
    update_max<<<1, 64, 0, stream>>>(st, slot, s);
    apply_acc<<<dim3(3,43,2), 256, 0, stream>>>(k3_out, rad, st, unnorm, sumw);
  }
  finalize_out<<<dim3(347,2), 256, 0, stream>>>(unnorm, sumw, out);
}

// Round 9
// 3016.428 us; speedup vs baseline: 2.2568x; 1.1437x over previous
//
#include <hip/hip_runtime.h>
#include <stdint.h>

typedef _Float16 half8 __attribute__((ext_vector_type(8)));
typedef _Float16 half4 __attribute__((ext_vector_type(4)));
typedef __attribute__((ext_vector_type(8))) short short8;
typedef __attribute__((ext_vector_type(4))) float f32x4;
typedef __attribute__((ext_vector_type(16))) float f32x16;

// ---------- helpers ----------
__device__ __forceinline__ unsigned encf(float x){                // monotonic f32->u32
  uint32_t u = __float_as_uint(x);
  return (u & 0x80000000u) ? ~u : (u | 0x80000000u);
}
__device__ __forceinline__ float decf(unsigned u){
  uint32_t b = (u & 0x80000000u) ? (u & 0x7FFFFFFFu) : ~u;
  return __uint_as_float(b);
}
__device__ __forceinline__ void gload16(const void* g, void* l){
  __builtin_amdgcn_global_load_lds(
      (const __attribute__((address_space(1))) void*)g,
      (__attribute__((address_space(3))) void*)l, 16, 0, 0);
}

// ---------- small utility kernels ----------
__global__ __launch_bounds__(256) void zero_u32(unsigned* __restrict__ p, int n){
  for (int i = blockIdx.x*256 + threadIdx.x; i < n; i += gridDim.x*256) p[i] = 0u;
}

// w (f32, [CO][CI][3][3]) -> wp (fp16, [kc16][tap][co_grp][32co x 16ch]) zero-padded.
// Per (kc,tap,grp) the 1KB region is exactly one wave a-frag (lane-contiguous).
__global__ __launch_bounds__(256) void pack_w(const float* __restrict__ w, _Float16* __restrict__ wp,
                                              int CO, int CI, int COP, int CINP){
  int idx = blockIdx.x*256 + threadIdx.x;
  int total = 9*COP*CINP;
  if (idx >= total) return;
  int ci = idx % CINP;
  int rest = idx / CINP;
  int co = rest % COP;
  int t  = rest / COP;
  float v = 0.f;
  if (co < CO && ci < CI) v = w[((size_t)co*CI + ci)*9 + t];
  int kc = ci >> 4, chl = ci & 15;
  wp[(((size_t)kc*9 + t)*(COP/32) + (co>>5))*512 + (co&31)*16 + chl] = (_Float16)v;
}

__global__ __launch_bounds__(256) void pack_bias(const float* __restrict__ b, float* __restrict__ bp, int n, int npad){
  int i = blockIdx.x*256 + threadIdx.x;
  if (i < npad) bp[i] = (i < n) ? b[i] : 0.f;
}

// features f32 [16][36864] -> rnn_in (halo 194x194, interior at +1,+1) ch0..15
//                             k1_in (192x192) ch128..143
// if copy_state: k1_in ch0..127 (state) -> rnn_in ch16..143. batch = blockIdx.y.
__global__ __launch_bounds__(256) void pack_feat(const float* __restrict__ f,
                                                 _Float16* __restrict__ rnn_in,
                                                 _Float16* __restrict__ k1_in,
                                                 int copy_state,
                                                 unsigned fbstr, unsigned rbstr, unsigned kbstr){
  int p = blockIdx.x*256 + threadIdx.x;
  if (p >= 36864) return;
  int b = blockIdx.y;
  int y = p / 192, x = p % 192;
  const float* fb = f + (size_t)b*fbstr;
  _Float16* r = rnn_in + (size_t)b*rbstr + ((size_t)(y+1)*194 + (x+1))*160;
  _Float16* k = k1_in  + (size_t)b*kbstr + (size_t)p*160;
  #pragma unroll
  for (int c = 0; c < 16; ++c){
    _Float16 v = (_Float16)fb[c*36864 + p];
    r[c] = v;
    k[128 + c] = v;
  }
  if (copy_state){
    #pragma unroll
    for (int cc = 0; cc < 128; cc += 8)
      *reinterpret_cast<short8*>(r + 16 + cc) = *reinterpret_cast<const short8*>(k + cc);
  }
}

// ---------- conv3x3: 32x32x16-MFMA implicit GEMM, LDS double-buffered ----------
// block = 256 threads = 4 waves; wave wid owns NR row-groups (rows yb+wid*NR+n), 32 cols,
// 128 couts (4 grps of 32). Per (kc16,tap) per wave: 4 KB weights (L1-hot), NR ds_read_b128,
// 4*NR MFMA 32x32x16 -> L1 bytes/MFMA halve at NR=2 (the round-8 L1 wall).
// Weights: [kc16][tap][grp][32co x 16ch]; a-frag = contiguous 1KB/wave.
// Acts: LDS dbuf [row 4NR+2][col34][ch16], staged via global_load_lds (lane-linear).
// All convs VALID-style (rnn uses zeroed halo buffer); OOB-ish reads land in
// allocation slack and only feed store-masked dead outputs.
template<int CINP, int NR, int MINW, bool RELU, bool K3>
__global__ __launch_bounds__(256, MINW) void conv3(
    const _Float16* __restrict__ X, int Wst, unsigned xbstr,
    const _Float16* __restrict__ Wp, int COP,
    const float* __restrict__ bias,
    _Float16* __restrict__ Y, int Wst_out, int DCP, unsigned ybstr,
    unsigned* __restrict__ slot, int Ho, int Wo,
    int nco_mask, int nco_shift)
{
  constexpr int KC = CINP/16;
  constexpr int SROWS = 4*NR + 2;
  constexpr int ITEMS = SROWS*34*2;            // 16B items per buffer
  constexpr int NRND  = (ITEMS + 255)/256;
  __shared__ _Float16 lds[2][ITEMS*8];

  const int tid  = threadIdx.x;
  const int lane = tid & 63;
  const int wid  = tid >> 6;
  const int l31  = lane & 31;
  const int hsel = lane >> 5;
  const int xb   = blockIdx.x * 32;
  const int yb   = blockIdx.y * (4*NR);
  const int co_blk = blockIdx.z & nco_mask;
  const int b      = blockIdx.z >> nco_shift;
  const int co_base = co_blk * 128;

  const _Float16* Xb = X + (size_t)b * xbstr;

  // stage addresses: ITEMS 16B items = [row SROWS][col34][half2]
  uint32_t goff[NRND];
  #pragma unroll
  for (int k = 0; k < NRND; ++k){
    int item = k*256 + tid;
    if (item < ITEMS){
      int row  = item / 68;
      int rem  = item % 68;
      int col  = rem >> 1;
      int half = rem & 1;
      int pix  = (yb + row)*Wst + xb + col;
      goff[k] = (uint32_t)(((uint32_t)pix*CINP + half*8) * 2);   // bytes
    } else goff[k] = 0;
  }

  auto stage = [&](int buf, int kc){
    const char* xp = (const char*)Xb + (size_t)kc*32;            // +16 channels
    char* lb = (char*)&lds[buf][0];
    #pragma unroll
    for (int k = 0; k < NRND; ++k){
      if (k*256 + tid < ITEMS)
        gload16(xp + goff[k], lb + k*4096 + wid*1024);
    }
  };

  // b-frag element offsets: boffe[n] + (ky*34 + kx)*16
  uint32_t boffe[NR];
  #pragma unroll
  for (int n = 0; n < NR; ++n)
    boffe[n] = (uint32_t)(((wid*NR + n)*34 + l31)*16 + hsel*8);

  f32x16 acc[NR][4] = {};
  const _Float16* wlane = Wp + ((size_t)co_blk*4)*512 + l31*16 + hsel*8;
  const int NG = COP/32;

  stage(0, 0);
  __syncthreads();
  for (int kc = 0; kc < KC; ++kc){
    if (kc + 1 < KC) stage((kc+1)&1, kc+1);
    const _Float16* wt = wlane + (size_t)(kc*9)*NG*512;
    const _Float16* lb = &lds[kc&1][0];
    half8 wreg[4], breg[2][NR];
    #pragma unroll
    for (int n = 0; n < NR; ++n)
      breg[0][n] = *reinterpret_cast<const half8*>(lb + boffe[n]);
    #pragma unroll
    for (int t = 0; t < 9; ++t){
      const int cur = t & 1, nxt = cur ^ 1;
      #pragma unroll
      for (int g = 0; g < 4; ++g)
        wreg[g] = *reinterpret_cast<const half8*>(wt + (size_t)t*NG*512 + g*512);
      if (t < 8){
        const int ky = (t+1)/3, kx = (t+1) - ky*3;
        #pragma unroll
        for (int n = 0; n < NR; ++n)
          breg[nxt][n] = *reinterpret_cast<const half8*>(lb + boffe[n] + (ky*34 + kx)*16);
      }
      #pragma unroll
      for (int n = 0; n < NR; ++n)
        #pragma unroll
        for (int g = 0; g < 4; ++g)
          acc[n][g] = __builtin_amdgcn_mfma_f32_32x32x16_f16(wreg[g], breg[cur][n], acc[n][g], 0, 0, 0);
    }
    if (kc + 1 < KC) __syncthreads();
  }

  // ---- epilogue ----
  // C/D: px = xb + l31; co = co_base + g*32 + 4*hsel + 8*q + j (reg = q*4+j)
  const int x = xb + l31;
  float lmax = -3.0e38f;
  #pragma unroll
  for (int n = 0; n < NR; ++n){
    const int y = yb + wid*NR + n;
    if (y < Ho && x < Wo){
      #pragma unroll
      for (int g = 0; g < 4; ++g){
        #pragma unroll
        for (int q = 0; q < 4; ++q){
          const int cb = co_base + g*32 + 4*hsel + 8*q;   // 4 consecutive couts
          f32x4 bs = *reinterpret_cast<const f32x4*>(bias + cb);
          float v[4];
          #pragma unroll
          for (int j = 0; j < 4; ++j){
            float tv = acc[n][g][q*4 + j] + bs[j];
            if (RELU) tv = tv > 0.f ? tv : 0.01f*tv;
            v[j] = tv;
          }
          if constexpr (!K3){
            half4 pk;
            #pragma unroll
            for (int j = 0; j < 4; ++j) pk[j] = (_Float16)v[j];
            *reinterpret_cast<half4*>(Y + (size_t)b*ybstr + ((size_t)y*Wst_out + x)*DCP + cb) = pk;
          } else {
            _Float16* yp = Y + (size_t)b*ybstr;
            #pragma unroll
            for (int j = 0; j < 4; ++j){
              if (cb + j < 441){
                yp[(size_t)(cb+j)*34596 + (size_t)y*186 + x] = (_Float16)v[j];
                lmax = fmaxf(lmax, v[j]);
              }
            }
          }
        }
      }
    }
  }
  if constexpr (K3){
    #pragma unroll
    for (int o = 32; o > 0; o >>= 1) lmax = fmaxf(lmax, __shfl_xor(lmax, o));
    if (lane == 0) atomicMax(slot + b, encf(lmax));
  }
}

// streaming-max state update per batch: st[2b]=M, st[2b+1]=scale; resets slot
__global__ void update_max(float* __restrict__ st, unsigned* __restrict__ slot, int step){
  int b = threadIdx.x;
  if (b < 2){
    float nm   = decf(slot[b]);
    float oldM = st[2*b];
    float M    = (step == 0) ? nm : fmaxf(oldM, nm);
    st[2*b+1] = (step == 0) ? 0.f : expf(oldM - M);
    st[2*b]   = M;
    slot[b] = 0u;
  }
}

// per-pixel: w_t = exp(k3[t][y+7][x+7]-M); unnorm = unnorm*scale + sum_t w_t*rad
__global__ __launch_bounds__(256) void apply_acc(
    const _Float16* __restrict__ k3out, const float* __restrict__ rad,
    const float* __restrict__ st,
    float* __restrict__ unnorm, float* __restrict__ sumw)
{
  const int tx = threadIdx.x & 63, ty = threadIdx.x >> 6;
  const int x = blockIdx.x*64 + tx;
  const int y = blockIdx.y*4 + ty;
  const int b = blockIdx.z;
  if (x >= 172 || y >= 172) return;
  const float M = st[2*b], scale = st[2*b+1];
  const _Float16* kp = k3out + (size_t)b*15256836 + (size_t)(y+7)*186 + (x+7);
  const float* rb = rad + (size_t)b*884736;          // 8*3*36864
  float a0 = 0.f, a1 = 0.f, a2 = 0.f, aw = 0.f;
  for (int dy = 0; dy < 21; ++dy){
    const float* r0 = rb + (size_t)(y+dy)*192 + x;
    #pragma unroll
    for (int dx = 0; dx < 21; ++dx){
      float w = __expf((float)kp[(size_t)(dy*21+dx)*34596] - M);
      aw += w;
      a0 += w * r0[dx];
      a1 += w * r0[36864 + dx];
      a2 += w * r0[73728 + dx];
    }
  }
  size_t p = (size_t)b*88752 + (size_t)y*172 + x;
  size_t ps = (size_t)b*29584 + (size_t)y*172 + x;
  unnorm[p]        = unnorm[p]*scale        + a0;
  unnorm[p+29584]  = unnorm[p+29584]*scale  + a1;
  unnorm[p+59168]  = unnorm[p+59168]*scale  + a2;
  sumw[ps]         = sumw[ps]*scale         + aw;
}

__global__ __launch_bounds__(256) void finalize_out(const float* __restrict__ unnorm,
                                                    const float* __restrict__ sumw,
                                                    float* __restrict__ out){
  int i = blockIdx.x*256 + threadIdx.x;
  int b = blockIdx.y;
  if (i >= 88752) return;
  int p = i % 29584;
  out[(size_t)b*88752 + i] = unnorm[(size_t)b*88752 + i] / (sumw[(size_t)b*29584 + p] + 1e-8f);
}

// ---------- host ----------
extern "C" void kernel_launch(void* const* d_in, const int* in_sizes, int n_in,
                              void* d_out, int out_size, void* d_ws, size_t ws_size,
                              hipStream_t stream) {
  const float* features = (const float*)d_in[0];
  const float* radiance = (const float*)d_in[1];
  const float* w_rnn = (const float*)d_in[2];
  const float* b_rnn = (const float*)d_in[3];
  const float* w_k1  = (const float*)d_in[4];
  const float* b_k1  = (const float*)d_in[5];
  const float* w_k2  = (const float*)d_in[6];
  const float* b_k2  = (const float*)d_in[7];
  const float* w_k3  = (const float*)d_in[8];
  const float* b_k3  = (const float*)d_in[9];
  float* out = (float*)d_out;

  char* ws = (char*)d_ws;
  size_t off = 0;
  auto alloc = [&](size_t bytes)->char*{
    char* p = ws + off;
    off = (off + bytes + 255) & ~(size_t)255;
    return p;
  };
  _Float16* wp_rnn   = (_Float16*)alloc((size_t)9*128*160*2);
  _Float16* wp_k1    = (_Float16*)alloc((size_t)9*128*160*2);
  _Float16* wp_k2    = (_Float16*)alloc((size_t)9*128*128*2);
  _Float16* wp_k3    = (_Float16*)alloc((size_t)9*512*128*2);
  float*    bias_k3p = (float*)   alloc((size_t)512*4);
  // per-batch strides (elements)
  const unsigned RB = 194u*194u*160u;            // rnn_in
  const unsigned KB = (192u*192u+448u)*160u;     // k1_in
  const unsigned K2B = (190u*190u+444u)*128u;    // k2_in
  const unsigned K3B = (194u*188u+256u)*128u;    // k3_in (+slack for 8-row k3 tiles)
  const unsigned KOB = 441u*34596u;              // k3_out
  _Float16* rnn_in = (_Float16*)alloc((size_t)2*RB*2);
  _Float16* k1_in  = (_Float16*)alloc((size_t)2*KB*2);
  _Float16* k2_in  = (_Float16*)alloc((size_t)2*K2B*2);
  _Float16* k3_in  = (_Float16*)alloc((size_t)2*K3B*2);
  _Float16* k3_out = (_Float16*)alloc((size_t)2*KOB*2);
  float*    accz   = (float*)   alloc((size_t)236678*4);
  if (off > ws_size) return;  // workspace too small -> fail loudly (no OOB writes)

  float*    unnorm = accz;                 // [2][3][172][172]
  float*    sumw   = accz + 177504;        // [2][172][172]
  float*    st     = accz + 236672;        // [2][{M,scale}]
  unsigned* slot   = (unsigned*)(accz + 236676);  // [2]

  // weight prepack (pure function of inputs; runs every call)
  pack_w<<<(9*128*160+255)/256, 256, 0, stream>>>(w_rnn, wp_rnn, 128, 144, 128, 160);
  pack_w<<<(9*128*160+255)/256, 256, 0, stream>>>(w_k1,  wp_k1,  128, 144, 128, 160);
  pack_w<<<(9*128*128+255)/256, 256, 0, stream>>>(w_k2,  wp_k2,  128, 128, 128, 128);
  pack_w<<<(9*512*128+255)/256, 256, 0, stream>>>(w_k3,  wp_k3,  441, 128, 512, 128);
  pack_bias<<<2, 256, 0, stream>>>(b_k3, bias_k3p, 441, 512);

  // zero rnn halo+state (both batches) and accumulators
  zero_u32<<<2048, 256, 0, stream>>>((unsigned*)rnn_in, (int)(2*RB/2));
  zero_u32<<<925,  256, 0, stream>>>((unsigned*)accz, 236678);

  for (int s = 0; s < 8; ++s){
    const float* f   = features + (size_t)s*16*36864;   // batch stride 8*16*36864
    const float* rad = radiance + (size_t)s*3*36864;    // batch stride 8*3*36864
    pack_feat<<<dim3(144,2), 256, 0, stream>>>(f, rnn_in, k1_in, s > 0 ? 1 : 0,
                                               8u*16u*36864u, RB, KB);
    // rnn: 144(160)->128 SAME via zero halo, lrelu; -> k1_in ch0..127
    conv3<160,1,3,true ,false><<<dim3(6,48,2), 256, 0, stream>>>(
        rnn_in, 194, RB, wp_rnn, 128, b_rnn, k1_in, 192, 160, KB,
        nullptr, 192, 192, 0, 0);
    // k1: 144(160)->128 VALID, lrelu; -> k2_in (190x190)
    conv3<160,1,3,true ,false><<<dim3(6,48,2), 256, 0, stream>>>(
        k1_in, 192, KB, wp_k1, 128, b_k1, k2_in, 190, 128, K2B,
        nullptr, 190, 190, 0, 0);
    // k2: 128->128 VALID, lrelu; -> k3_in (188x188)
    conv3<128,1,3,true ,false><<<dim3(6,47,2), 256, 0, stream>>>(
        k2_in, 190, K2B, wp_k2, 128, b_k2, k3_in, 188, 128, K3B,
        nullptr, 188, 188, 0, 0);
    // k3: 128->441(512 pad, 4 slices) VALID, no relu; NR=2 (8-row tile) -> fp16 planes + max
    conv3<128,2,2,false,true ><<<dim3(6,24,8), 256, 0, stream>>>(
        k3_in, 188, K3B, wp_k3, 512, bias_k3p, k3_out, 0, 0, KOB,
        slot, 186, 186, 3, 2);
    update_max<<<1, 64, 0, stream>>>(st, slot, s);
    apply_acc<<<dim3(3,43,2), 256, 0, stream>>>(k3_out, rad, st, unnorm, sumw);
  }
  finalize_out<<<dim3(347,2), 256, 0, stream>>>(unnorm, sumw, out);
}

// Round 10
// 2719.764 us; speedup vs baseline: 2.5030x; 1.1091x over previous
//
#include <hip/hip_runtime.h>
#include <stdint.h>

typedef _Float16 half8 __attribute__((ext_vector_type(8)));
typedef _Float16 half4 __attribute__((ext_vector_type(4)));
typedef __attribute__((ext_vector_type(8))) short short8;
typedef __attribute__((ext_vector_type(4))) float f32x4;
typedef __attribute__((ext_vector_type(16))) float f32x16;

// ---------- helpers ----------
__device__ __forceinline__ unsigned encf(float x){                // monotonic f32->u32
  uint32_t u = __float_as_uint(x);
  return (u & 0x80000000u) ? ~u : (u | 0x80000000u);
}
__device__ __forceinline__ float decf(unsigned u){
  uint32_t b = (u & 0x80000000u) ? (u & 0x7FFFFFFFu) : ~u;
  return __uint_as_float(b);
}
__device__ __forceinline__ void gload16(const void* g, void* l){
  __builtin_amdgcn_global_load_lds(
      (const __attribute__((address_space(1))) void*)g,
      (__attribute__((address_space(3))) void*)l, 16, 0, 0);
}

// ---------- small utility kernels ----------
__global__ __launch_bounds__(256) void zero_u32(unsigned* __restrict__ p, int n){
  for (int i = blockIdx.x*256 + threadIdx.x; i < n; i += gridDim.x*256) p[i] = 0u;
}

// w (f32, [CO][CI][3][3]) -> wp (fp16, [kc16][tap][co_grp][32co x 16ch]) zero-padded.
// Per (kc,tap,grp) the 1KB region is exactly one wave a-frag (lane-contiguous).
__global__ __launch_bounds__(256) void pack_w(const float* __restrict__ w, _Float16* __restrict__ wp,
                                              int CO, int CI, int COP, int CINP){
  int idx = blockIdx.x*256 + threadIdx.x;
  int total = 9*COP*CINP;
  if (idx >= total) return;
  int ci = idx % CINP;
  int rest = idx / CINP;
  int co = rest % COP;
  int t  = rest / COP;
  float v = 0.f;
  if (co < CO && ci < CI) v = w[((size_t)co*CI + ci)*9 + t];
  int kc = ci >> 4, chl = ci & 15;
  wp[(((size_t)kc*9 + t)*(COP/32) + (co>>5))*512 + (co&31)*16 + chl] = (_Float16)v;
}

__global__ __launch_bounds__(256) void pack_bias(const float* __restrict__ b, float* __restrict__ bp, int n, int npad){
  int i = blockIdx.x*256 + threadIdx.x;
  if (i < npad) bp[i] = (i < n) ? b[i] : 0.f;
}

// features f32 [16][36864] -> rnn_in (halo 194x194, interior at +1,+1) ch0..15
//                             k1_in (192x192) ch128..143
// if copy_state: k1_in ch0..127 (state) -> rnn_in ch16..143. batch = blockIdx.y.
__global__ __launch_bounds__(256) void pack_feat(const float* __restrict__ f,
                                                 _Float16* __restrict__ rnn_in,
                                                 _Float16* __restrict__ k1_in,
                                                 int copy_state,
                                                 unsigned fbstr, unsigned rbstr, unsigned kbstr){
  int p = blockIdx.x*256 + threadIdx.x;
  if (p >= 36864) return;
  int b = blockIdx.y;
  int y = p / 192, x = p % 192;
  const float* fb = f + (size_t)b*fbstr;
  _Float16* r = rnn_in + (size_t)b*rbstr + ((size_t)(y+1)*194 + (x+1))*160;
  _Float16* k = k1_in  + (size_t)b*kbstr + (size_t)p*160;
  #pragma unroll
  for (int c = 0; c < 16; ++c){
    _Float16 v = (_Float16)fb[c*36864 + p];
    r[c] = v;
    k[128 + c] = v;
  }
  if (copy_state){
    #pragma unroll
    for (int cc = 0; cc < 128; cc += 8)
      *reinterpret_cast<short8*>(r + 16 + cc) = *reinterpret_cast<const short8*>(k + cc);
  }
}

// ---------- conv3x3: 32x32x16-MFMA implicit GEMM, G=2/N=4, 2-wave blocks ----------
// block = 128 threads = 2 waves; wave wid owns co-groups {2wid, 2wid+1} (64 couts),
// 4 rows (yb..yb+3), 32 cols. Block tile: 128 co x 4 rows x 32 cols.
// Per (kc16,tap) per wave: 2 KB weights (L1), 4 ds_read_b128, 8 MFMA 32x32x16.
// Rate model (L1 64B/cyc, LDS 128B/cyc): L1 32 cyc : LDS 32 cyc : MFMA 16 CU-cyc
//   -> 50% MfmaUtil ceiling (2x the round-9 G4N2 structure).
// Weights: [kc16][tap][grp][32co x 16ch]; a-frag = contiguous 1KB per grp.
// Acts: LDS dbuf [row6][col34][ch16] = 6528 B/buf, staged via global_load_lds.
// All convs VALID-style (rnn uses zeroed halo buffer); OOB-ish reads land in
// allocation slack and only feed store-masked dead outputs.
template<int CINP, bool RELU, bool K3>
__global__ __launch_bounds__(128, 2) void conv3(
    const _Float16* __restrict__ X, int Wst, unsigned xbstr,
    const _Float16* __restrict__ Wp, int COP,
    const float* __restrict__ bias,
    _Float16* __restrict__ Y, int Wst_out, int DCP, unsigned ybstr,
    unsigned* __restrict__ slot, int Ho, int Wo,
    int nco_mask, int nco_shift)
{
  constexpr int KC = CINP/16;
  constexpr int ITEMS = 6*34*2;                // 408 16B items per buffer
  __shared__ _Float16 lds[2][ITEMS*8];

  const int tid  = threadIdx.x;
  const int lane = tid & 63;
  const int wid  = tid >> 6;                   // 0..1 : co half
  const int l31  = lane & 31;
  const int hsel = lane >> 5;
  const int xb   = blockIdx.x * 32;
  const int yb   = blockIdx.y * 4;
  const int co_blk = blockIdx.z & nco_mask;
  const int b      = blockIdx.z >> nco_shift;
  const int co_base = co_blk * 128;

  const _Float16* Xb = X + (size_t)b * xbstr;

  // stage addresses: 408 16B items = [row6][col34][half2]
  uint32_t goff[4];
  #pragma unroll
  for (int k = 0; k < 4; ++k){
    int item = k*128 + tid;
    if (item < ITEMS){
      int row  = item / 68;
      int rem  = item % 68;
      int col  = rem >> 1;
      int half = rem & 1;
      int pix  = (yb + row)*Wst + xb + col;
      goff[k] = (uint32_t)(((uint32_t)pix*CINP + half*8) * 2);   // bytes
    } else goff[k] = 0;
  }

  auto stage = [&](int buf, int kc){
    const char* xp = (const char*)Xb + (size_t)kc*32;            // +16 channels
    char* lb = (char*)&lds[buf][0];
    #pragma unroll
    for (int k = 0; k < 4; ++k){
      if (k*128 + tid < ITEMS)
        gload16(xp + goff[k], lb + k*2048 + wid*1024);
    }
  };

  // b-frag element offsets: boffe[n] + (ky*34 + kx)*16
  uint32_t boffe[4];
  #pragma unroll
  for (int n = 0; n < 4; ++n)
    boffe[n] = (uint32_t)((n*34 + l31)*16 + hsel*8);

  f32x16 acc[4][2] = {};
  const _Float16* wlane = Wp + ((size_t)(co_blk*4 + wid*2))*512 + l31*16 + hsel*8;
  const int NG = COP/32;

  stage(0, 0);
  __syncthreads();
  for (int kc = 0; kc < KC; ++kc){
    if (kc + 1 < KC) stage((kc+1)&1, kc+1);
    const _Float16* wt = wlane + (size_t)(kc*9)*NG*512;
    const _Float16* lb = &lds[kc&1][0];
    half8 wreg[2], breg[2][4];
    #pragma unroll
    for (int n = 0; n < 4; ++n)
      breg[0][n] = *reinterpret_cast<const half8*>(lb + boffe[n]);
    #pragma unroll
    for (int t = 0; t < 9; ++t){
      const int cur = t & 1, nxt = cur ^ 1;
      #pragma unroll
      for (int g = 0; g < 2; ++g)
        wreg[g] = *reinterpret_cast<const half8*>(wt + (size_t)t*NG*512 + g*512);
      if (t < 8){
        const int ky = (t+1)/3, kx = (t+1) - ky*3;
        #pragma unroll
        for (int n = 0; n < 4; ++n)
          breg[nxt][n] = *reinterpret_cast<const half8*>(lb + boffe[n] + (ky*34 + kx)*16);
      }
      #pragma unroll
      for (int n = 0; n < 4; ++n)
        #pragma unroll
        for (int g = 0; g < 2; ++g)
          acc[n][g] = __builtin_amdgcn_mfma_f32_32x32x16_f16(wreg[g], breg[cur][n], acc[n][g], 0, 0, 0);
    }
    if (kc + 1 < KC) __syncthreads();
  }

  // ---- epilogue ----
  // C/D: px = xb + l31; co = co_base + (wid*2+g)*32 + 4*hsel + 8*q + j (reg = q*4+j)
  const int x = xb + l31;
  float lmax = -3.0e38f;
  #pragma unroll
  for (int n = 0; n < 4; ++n){
    const int y = yb + n;
    if (y < Ho && x < Wo){
      #pragma unroll
      for (int g = 0; g < 2; ++g){
        #pragma unroll
        for (int q = 0; q < 4; ++q){
          const int cb = co_base + (wid*2 + g)*32 + 4*hsel + 8*q;   // 4 consecutive couts
          f32x4 bs = *reinterpret_cast<const f32x4*>(bias + cb);
          float v[4];
          #pragma unroll
          for (int j = 0; j < 4; ++j){
            float tv = acc[n][g][q*4 + j] + bs[j];
            if (RELU) tv = tv > 0.f ? tv : 0.01f*tv;
            v[j] = tv;
          }
          if constexpr (!K3){
            half4 pk;
            #pragma unroll
            for (int j = 0; j < 4; ++j) pk[j] = (_Float16)v[j];
            *reinterpret_cast<half4*>(Y + (size_t)b*ybstr + ((size_t)y*Wst_out + x)*DCP + cb) = pk;
          } else {
            _Float16* yp = Y + (size_t)b*ybstr;
            #pragma unroll
            for (int j = 0; j < 4; ++j){
              if (cb + j < 441){
                yp[(size_t)(cb+j)*34596 + (size_t)y*186 + x] = (_Float16)v[j];
                lmax = fmaxf(lmax, v[j]);
              }
            }
          }
        }
      }
    }
  }
  if constexpr (K3){
    #pragma unroll
    for (int o = 32; o > 0; o >>= 1) lmax = fmaxf(lmax, __shfl_xor(lmax, o));
    if (lane == 0) atomicMax(slot + b, encf(lmax));
  }
}

// streaming-max state update per batch: st[2b]=M, st[2b+1]=scale; resets slot
__global__ void update_max(float* __restrict__ st, unsigned* __restrict__ slot, int step){
  int b = threadIdx.x;
  if (b < 2){
    float nm   = decf(slot[b]);
    float oldM = st[2*b];
    float M    = (step == 0) ? nm : fmaxf(oldM, nm);
    st[2*b+1] = (step == 0) ? 0.f : expf(oldM - M);
    st[2*b]   = M;
    slot[b] = 0u;
  }
}

// per-pixel: w_t = exp(k3[t][y+7][x+7]-M); unnorm = unnorm*scale + sum_t w_t*rad
__global__ __launch_bounds__(256) void apply_acc(
    const _Float16* __restrict__ k3out, const float* __restrict__ rad,
    const float* __restrict__ st,
    float* __restrict__ unnorm, float* __restrict__ sumw)
{
  const int tx = threadIdx.x & 63, ty = threadIdx.x >> 6;
  const int x = blockIdx.x*64 + tx;
  const int y = blockIdx.y*4 + ty;
  const int b = blockIdx.z;
  if (x >= 172 || y >= 172) return;
  const float M = st[2*b], scale = st[2*b+1];
  const _Float16* kp = k3out + (size_t)b*15256836 + (size_t)(y+7)*186 + (x+7);
  const float* rb = rad + (size_t)b*884736;          // 8*3*36864
  float a0 = 0.f, a1 = 0.f, a2 = 0.f, aw = 0.f;
  for (int dy = 0; dy < 21; ++dy){
    const float* r0 = rb + (size_t)(y+dy)*192 + x;
    #pragma unroll
    for (int dx = 0; dx < 21; ++dx){
      float w = __expf((float)kp[(size_t)(dy*21+dx)*34596] - M);
      aw += w;
      a0 += w * r0[dx];
      a1 += w * r0[36864 + dx];
      a2 += w * r0[73728 + dx];
    }
  }
  size_t p = (size_t)b*88752 + (size_t)y*172 + x;
  size_t ps = (size_t)b*29584 + (size_t)y*172 + x;
  unnorm[p]        = unnorm[p]*scale        + a0;
  unnorm[p+29584]  = unnorm[p+29584]*scale  + a1;
  unnorm[p+59168]  = unnorm[p+59168]*scale  + a2;
  sumw[ps]         = sumw[ps]*scale         + aw;
}

__global__ __launch_bounds__(256) void finalize_out(const float* __restrict__ unnorm,
                                                    const float* __restrict__ sumw,
                                                    float* __restrict__ out){
  int i = blockIdx.x*256 + threadIdx.x;
  int b = blockIdx.y;
  if (i >= 88752) return;
  int p = i % 29584;
  out[(size_t)b*88752 + i] = unnorm[(size_t)b*88752 + i] / (sumw[(size_t)b*29584 + p] + 1e-8f);
}

// ---------- host ----------
extern "C" void kernel_launch(void* const* d_in, const int* in_sizes, int n_in,
                              void* d_out, int out_size, void* d_ws, size_t ws_size,
                              hipStream_t stream) {
  const float* features = (const float*)d_in[0];
  const float* radiance = (const float*)d_in[1];
  const float* w_rnn = (const float*)d_in[2];
  const float* b_rnn = (const float*)d_in[3];
  const float* w_k1  = (const float*)d_in[4];
  const float* b_k1  = (const float*)d_in[5];
  const float* w_k2  = (const float*)d_in[6];
  const float* b_k2  = (const float*)d_in[7];
  const float* w_k3  = (const float*)d_in[8];
  const float* b_k3  = (const float*)d_in[9];
  float* out = (float*)d_out;

  char* ws = (char*)d_ws;
  size_t off = 0;
  auto alloc = [&](size_t bytes)->char*{
    char* p = ws + off;
    off = (off + bytes + 255) & ~(size_t)255;
    return p;
  };
  _Float16* wp_rnn   = (_Float16*)alloc((size_t)9*128*160*2);
  _Float16* wp_k1    = (_Float16*)alloc((size_t)9*128*160*2);
  _Float16* wp_k2    = (_Float16*)alloc((size_t)9*128*128*2);
  _Float16* wp_k3    = (_Float16*)alloc((size_t)9*512*128*2);
  float*    bias_k3p = (float*)   alloc((size_t)512*4);
  // per-batch strides (elements)
  const unsigned RB = 194u*194u*160u;            // rnn_in
  const unsigned KB = (192u*192u+448u)*160u;     // k1_in
  const unsigned K2B = (190u*190u+444u)*128u;    // k2_in
  const unsigned K3B = (194u*188u+256u)*128u;    // k3_in (+slack)
  const unsigned KOB = 441u*34596u;              // k3_out
  _Float16* rnn_in = (_Float16*)alloc((size_t)2*RB*2);
  _Float16* k1_in  = (_Float16*)alloc((size_t)2*KB*2);
  _Float16* k2_in  = (_Float16*)alloc((size_t)2*K2B*2);
  _Float16* k3_in  = (_Float16*)alloc((size_t)2*K3B*2);
  _Float16* k3_out = (_Float16*)alloc((size_t)2*KOB*2);
  float*    accz   = (float*)   alloc((size_t)236678*4);
  if (off > ws_size) return;  // workspace too small -> fail loudly (no OOB writes)

  float*    unnorm = accz;                 // [2][3][172][172]
  float*    sumw   = accz + 177504;        // [2][172][172]
  float*    st     = accz + 236672;        // [2][{M,scale}]
  unsigned* slot   = (unsigned*)(accz + 236676);  // [2]

  // weight prepack (pure function of inputs; runs every call)
  pack_w<<<(9*128*160+255)/256, 256, 0, stream>>>(w_rnn, wp_rnn, 128, 144, 128, 160);
  pack_w<<<(9*128*160+255)/256, 256, 0, stream>>>(w_k1,  wp_k1,  128, 144, 128, 160);
  pack_w<<<(9*128*128+255)/256, 256, 0, stream>>>(w_k2,  wp_k2,  128, 128, 128, 128);
  pack_w<<<(9*512*128+255)/256, 256, 0, stream>>>(w_k3,  wp_k3,  441, 128, 512, 128);
  pack_bias<<<2, 256, 0, stream>>>(b_k3, bias_k3p, 441, 512);

  // zero rnn halo+state (both batches) and accumulators
  zero_u32<<<2048, 256, 0, stream>>>((unsigned*)rnn_in, (int)(2*RB/2));
  zero_u32<<<925,  256, 0, stream>>>((unsigned*)accz, 236678);

  for (int s = 0; s < 8; ++s){
    const float* f   = features + (size_t)s*16*36864;   // batch stride 8*16*36864
    const float* rad = radiance + (size_t)s*3*36864;    // batch stride 8*3*36864
    pack_feat<<<dim3(144,2), 256, 0, stream>>>(f, rnn_in, k1_in, s > 0 ? 1 : 0,
                                               8u*16u*36864u, RB, KB);
    // rnn: 144(160)->128 SAME via zero halo, lrelu; -> k1_in ch0..127
    conv3<160,true ,false><<<dim3(6,48,2), 128, 0, stream>>>(
        rnn_in, 194, RB, wp_rnn, 128, b_rnn, k1_in, 192, 160, KB,
        nullptr, 192, 192, 0, 0);
    // k1: 144(160)->128 VALID, lrelu; -> k2_in (190x190)
    conv3<160,true ,false><<<dim3(6,48,2), 128, 0, stream>>>(
        k1_in, 192, KB, wp_k1, 128, b_k1, k2_in, 190, 128, K2B,
        nullptr, 190, 190, 0, 0);
    // k2: 128->128 VALID, lrelu; -> k3_in (188x188)
    conv3<128,true ,false><<<dim3(6,47,2), 128, 0, stream>>>(
        k2_in, 190, K2B, wp_k2, 128, b_k2, k3_in, 188, 128, K3B,
        nullptr, 188, 188, 0, 0);
    // k3: 128->441(512 pad, 4 slices) VALID, no relu; -> fp16 planes + atomic max
    conv3<128,false,true ><<<dim3(6,47,8), 128, 0, stream>>>(
        k3_in, 188, K3B, wp_k3, 512, bias_k3p, k3_out, 0, 0, KOB,
        slot, 186, 186, 3, 2);
    update_max<<<1, 64, 0, stream>>>(st, slot, s);
    apply_acc<<<dim3(3,43,2), 256, 0, stream>>>(k3_out, rad, st, unnorm, sumw);
  }
  finalize_out<<<dim3(347,2), 256, 0, stream>>>(unnorm, sumw, out);
}

// Round 11
// 2551.575 us; speedup vs baseline: 2.6679x; 1.0659x over previous
//
#include <hip/hip_runtime.h>
#include <stdint.h>

typedef _Float16 half8 __attribute__((ext_vector_type(8)));
typedef _Float16 half4 __attribute__((ext_vector_type(4)));
typedef __attribute__((ext_vector_type(8))) short short8;
typedef __attribute__((ext_vector_type(4))) float f32x4;
typedef __attribute__((ext_vector_type(16))) float f32x16;

// ---------- helpers ----------
__device__ __forceinline__ unsigned encf(float x){                // monotonic f32->u32
  uint32_t u = __float_as_uint(x);
  return (u & 0x80000000u) ? ~u : (u | 0x80000000u);
}
__device__ __forceinline__ float decf(unsigned u){
  uint32_t b = (u & 0x80000000u) ? (u & 0x7FFFFFFFu) : ~u;
  return __uint_as_float(b);
}
__device__ __forceinline__ void gload16(const void* g, void* l){
  __builtin_amdgcn_global_load_lds(
      (const __attribute__((address_space(1))) void*)g,
      (__attribute__((address_space(3))) void*)l, 16, 0, 0);
}

// ---------- small utility kernels ----------
__global__ __launch_bounds__(256) void zero_u32(unsigned* __restrict__ p, int n){
  for (int i = blockIdx.x*256 + threadIdx.x; i < n; i += gridDim.x*256) p[i] = 0u;
}

// w (f32, [CO][CI][3][3]) -> wp (fp16, [kc16][tap][co_grp][32co x 16ch]) zero-padded.
// Per (kc,tap,grp) the 1KB region is exactly one wave a-frag (lane-contiguous).
__global__ __launch_bounds__(256) void pack_w(const float* __restrict__ w, _Float16* __restrict__ wp,
                                              int CO, int CI, int COP, int CINP){
  int idx = blockIdx.x*256 + threadIdx.x;
  int total = 9*COP*CINP;
  if (idx >= total) return;
  int ci = idx % CINP;
  int rest = idx / CINP;
  int co = rest % COP;
  int t  = rest / COP;
  float v = 0.f;
  if (co < CO && ci < CI) v = w[((size_t)co*CI + ci)*9 + t];
  int kc = ci >> 4, chl = ci & 15;
  wp[(((size_t)kc*9 + t)*(COP/32) + (co>>5))*512 + (co&31)*16 + chl] = (_Float16)v;
}

__global__ __launch_bounds__(256) void pack_bias(const float* __restrict__ b, float* __restrict__ bp, int n, int npad){
  int i = blockIdx.x*256 + threadIdx.x;
  if (i < npad) bp[i] = (i < n) ? b[i] : 0.f;
}

// features f32 [16][36864] -> rnn_in (halo 194x194, interior at +1,+1) ch0..15
//                             k1_in (192x192) ch128..143
// if copy_state: k1_in ch0..127 (state) -> rnn_in ch16..143. batch = blockIdx.y.
__global__ __launch_bounds__(256) void pack_feat(const float* __restrict__ f,
                                                 _Float16* __restrict__ rnn_in,
                                                 _Float16* __restrict__ k1_in,
                                                 int copy_state,
                                                 unsigned fbstr, unsigned rbstr, unsigned kbstr){
  int p = blockIdx.x*256 + threadIdx.x;
  if (p >= 36864) return;
  int b = blockIdx.y;
  int y = p / 192, x = p % 192;
  const float* fb = f + (size_t)b*fbstr;
  _Float16* r = rnn_in + (size_t)b*rbstr + ((size_t)(y+1)*194 + (x+1))*160;
  _Float16* k = k1_in  + (size_t)b*kbstr + (size_t)p*160;
  #pragma unroll
  for (int c = 0; c < 16; ++c){
    _Float16 v = (_Float16)fb[c*36864 + p];
    r[c] = v;
    k[128 + c] = v;
  }
  if (copy_state){
    #pragma unroll
    for (int cc = 0; cc < 128; cc += 8)
      *reinterpret_cast<short8*>(r + 16 + cc) = *reinterpret_cast<const short8*>(k + cc);
  }
}

// ---------- conv3x3: 32x32x16-MFMA implicit GEMM, G=2/N=4, 2-wave blocks ----------
// block = 128 threads = 2 waves; wave wid owns co-groups {2wid, 2wid+1} (64 couts),
// 4 rows, 32 cols. Block tile: 128 co x 4 rows x 32 cols.
// KEY (r10 fix): vmcnt completes IN ORDER, so weight loads issued after the
// per-kc stage() can't be consumed without draining the stage. Weights now run a
// rotated depth-3 pipeline (slot = t%3) whose refills at t=6..8 prefetch taps 0..2
// of kc+1 BEFORE the barrier & next stage issue -> taps 0-2 never wait on the
// stage; tap 3 is the single bounded join point per kc.
// Weights: [kc16][tap][grp][32co x 16ch] contiguous across kc (flat gtap index);
// +48KB slack absorbs the tail prefetch over-read.
// Acts: LDS dbuf [row6][col34][ch16], staged via global_load_lds.
// All convs VALID-style (rnn uses zeroed halo buffer); OOB-ish reads land in
// allocation slack and only feed store-masked dead outputs.
template<int CINP, bool RELU, bool K3>
__global__ __launch_bounds__(128, 2) void conv3(
    const _Float16* __restrict__ X, int Wst, unsigned xbstr,
    const _Float16* __restrict__ Wp, int COP,
    const float* __restrict__ bias,
    _Float16* __restrict__ Y, int Wst_out, int DCP, unsigned ybstr,
    unsigned* __restrict__ slot, int Ho, int Wo,
    int nco_mask, int nco_shift)
{
  constexpr int KC = CINP/16;
  constexpr int ITEMS = 6*34*2;                // 408 16B items per buffer
  __shared__ _Float16 lds[2][ITEMS*8];

  const int tid  = threadIdx.x;
  const int lane = tid & 63;
  const int wid  = tid >> 6;                   // 0..1 : co half
  const int l31  = lane & 31;
  const int hsel = lane >> 5;
  const int xb   = blockIdx.x * 32;
  const int yb   = blockIdx.y * 4;
  const int co_blk = blockIdx.z & nco_mask;
  const int b      = blockIdx.z >> nco_shift;
  const int co_base = co_blk * 128;

  const _Float16* Xb = X + (size_t)b * xbstr;

  // stage addresses: 408 16B items = [row6][col34][half2]
  uint32_t goff[4];
  #pragma unroll
  for (int k = 0; k < 4; ++k){
    int item = k*128 + tid;
    if (item < ITEMS){
      int row  = item / 68;
      int rem  = item % 68;
      int col  = rem >> 1;
      int half = rem & 1;
      int pix  = (yb + row)*Wst + xb + col;
      goff[k] = (uint32_t)(((uint32_t)pix*CINP + half*8) * 2);   // bytes
    } else goff[k] = 0;
  }

  auto stage = [&](int buf, int kc){
    const char* xp = (const char*)Xb + (size_t)kc*32;            // +16 channels
    char* lb = (char*)&lds[buf][0];
    #pragma unroll
    for (int k = 0; k < 4; ++k){
      if (k*128 + tid < ITEMS)
        gload16(xp + goff[k], lb + k*2048 + wid*1024);
    }
  };

  // b-frag element offsets: boffe[n] + (ky*34 + kx)*16
  uint32_t boffe[4];
  #pragma unroll
  for (int n = 0; n < 4; ++n)
    boffe[n] = (uint32_t)((n*34 + l31)*16 + hsel*8);

  f32x16 acc[4][2] = {};
  // flat weight base: addr(gtap, g) = wbase + (gtap*NG + g)*512
  const _Float16* wbase = Wp + ((size_t)(co_blk*4 + wid*2))*512 + l31*16 + hsel*8;
  const int NG = COP/32;

  half8 wreg[3][2];
  // prologue: taps 0,1,2 of kc=0 -> slots 0,1,2 (issued BEFORE stage(0))
  #pragma unroll
  for (int s3 = 0; s3 < 3; ++s3)
    #pragma unroll
    for (int g = 0; g < 2; ++g)
      wreg[s3][g] = *reinterpret_cast<const half8*>(wbase + ((size_t)s3*NG + g)*512);

  stage(0, 0);
  __syncthreads();
  for (int kc = 0; kc < KC; ++kc){
    if (kc + 1 < KC) stage((kc+1)&1, kc+1);
    const _Float16* lb = &lds[kc&1][0];
    half8 breg[2][4];
    #pragma unroll
    for (int n = 0; n < 4; ++n)
      breg[0][n] = *reinterpret_cast<const half8*>(lb + boffe[n]);
    #pragma unroll
    for (int t = 0; t < 9; ++t){
      const int cur = t & 1, nxt = cur ^ 1;
      if (t < 8){
        const int ky = (t+1)/3, kx = (t+1) - ky*3;
        #pragma unroll
        for (int n = 0; n < 4; ++n)
          breg[nxt][n] = *reinterpret_cast<const half8*>(lb + boffe[n] + (ky*34 + kx)*16);
      }
      #pragma unroll
      for (int n = 0; n < 4; ++n)
        #pragma unroll
        for (int g = 0; g < 2; ++g)
          acc[n][g] = __builtin_amdgcn_mfma_f32_32x32x16_f16(wreg[t%3][g], breg[cur][n], acc[n][g], 0, 0, 0);
      // refill consumed slot with tap (kc*9 + t + 3); crosses into kc+1 for t>=6.
      // reads past the end on the last kc land in the +48KB slack (never consumed).
      {
        const size_t gt = (size_t)(kc*9 + t + 3);
        #pragma unroll
        for (int g = 0; g < 2; ++g)
          wreg[t%3][g] = *reinterpret_cast<const half8*>(wbase + (gt*NG + g)*512);
      }
    }
    if (kc + 1 < KC) __syncthreads();
  }

  // ---- epilogue ----
  // C/D: px = xb + l31; co = co_base + (wid*2+g)*32 + 4*hsel + 8*q + j (reg = q*4+j)
  const int x = xb + l31;
  float lmax = -3.0e38f;
  #pragma unroll
  for (int n = 0; n < 4; ++n){
    const int y = yb + n;
    if (y < Ho && x < Wo){
      #pragma unroll
      for (int g = 0; g < 2; ++g){
        #pragma unroll
        for (int q = 0; q < 4; ++q){
          const int cb = co_base + (wid*2 + g)*32 + 4*hsel + 8*q;   // 4 consecutive couts
          f32x4 bs = *reinterpret_cast<const f32x4*>(bias + cb);
          float v[4];
          #pragma unroll
          for (int j = 0; j < 4; ++j){
            float tv = acc[n][g][q*4 + j] + bs[j];
            if (RELU) tv = tv > 0.f ? tv : 0.01f*tv;
            v[j] = tv;
          }
          if constexpr (!K3){
            half4 pk;
            #pragma unroll
            for (int j = 0; j < 4; ++j) pk[j] = (_Float16)v[j];
            *reinterpret_cast<half4*>(Y + (size_t)b*ybstr + ((size_t)y*Wst_out + x)*DCP + cb) = pk;
          } else {
            _Float16* yp = Y + (size_t)b*ybstr;
            #pragma unroll
            for (int j = 0; j < 4; ++j){
              if (cb + j < 441){
                yp[(size_t)(cb+j)*34596 + (size_t)y*186 + x] = (_Float16)v[j];
                lmax = fmaxf(lmax, v[j]);
              }
            }
          }
        }
      }
    }
  }
  if constexpr (K3){
    #pragma unroll
    for (int o = 32; o > 0; o >>= 1) lmax = fmaxf(lmax, __shfl_xor(lmax, o));
    if (lane == 0) atomicMax(slot + b, encf(lmax));
  }
}

// streaming-max state update per batch: st[2b]=M, st[2b+1]=scale; resets slot
__global__ void update_max(float* __restrict__ st, unsigned* __restrict__ slot, int step){
  int b = threadIdx.x;
  if (b < 2){
    float nm   = decf(slot[b]);
    float oldM = st[2*b];
    float M    = (step == 0) ? nm : fmaxf(oldM, nm);
    st[2*b+1] = (step == 0) ? 0.f : expf(oldM - M);
    st[2*b]   = M;
    slot[b] = 0u;
  }
}

// per-pixel: w_t = exp(k3[t][y+7][x+7]-M); unnorm = unnorm*scale + sum_t w_t*rad
__global__ __launch_bounds__(256) void apply_acc(
    const _Float16* __restrict__ k3out, const float* __restrict__ rad,
    const float* __restrict__ st,
    float* __restrict__ unnorm, float* __restrict__ sumw)
{
  const int tx = threadIdx.x & 63, ty = threadIdx.x >> 6;
  const int x = blockIdx.x*64 + tx;
  const int y = blockIdx.y*4 + ty;
  const int b = blockIdx.z;
  if (x >= 172 || y >= 172) return;
  const float M = st[2*b], scale = st[2*b+1];
  const _Float16* kp = k3out + (size_t)b*15256836 + (size_t)(y+7)*186 + (x+7);
  const float* rb = rad + (size_t)b*884736;          // 8*3*36864
  float a0 = 0.f, a1 = 0.f, a2 = 0.f, aw = 0.f;
  for (int dy = 0; dy < 21; ++dy){
    const float* r0 = rb + (size_t)(y+dy)*192 + x;
    #pragma unroll
    for (int dx = 0; dx < 21; ++dx){
      float w = __expf((float)kp[(size_t)(dy*21+dx)*34596] - M);
      aw += w;
      a0 += w * r0[dx];
      a1 += w * r0[36864 + dx];
      a2 += w * r0[73728 + dx];
    }
  }
  size_t p = (size_t)b*88752 + (size_t)y*172 + x;
  size_t ps = (size_t)b*29584 + (size_t)y*172 + x;
  unnorm[p]        = unnorm[p]*scale        + a0;
  unnorm[p+29584]  = unnorm[p+29584]*scale  + a1;
  unnorm[p+59168]  = unnorm[p+59168]*scale  + a2;
  sumw[ps]         = sumw[ps]*scale         + aw;
}

__global__ __launch_bounds__(256) void finalize_out(const float* __restrict__ unnorm,
                                                    const float* __restrict__ sumw,
                                                    float* __restrict__ out){
  int i = blockIdx.x*256 + threadIdx.x;
  int b = blockIdx.y;
  if (i >= 88752) return;
  int p = i % 29584;
  out[(size_t)b*88752 + i] = unnorm[(size_t)b*88752 + i] / (sumw[(size_t)b*29584 + p] + 1e-8f);
}

// ---------- host ----------
extern "C" void kernel_launch(void* const* d_in, const int* in_sizes, int n_in,
                              void* d_out, int out_size, void* d_ws, size_t ws_size,
                              hipStream_t stream) {
  const float* features = (const float*)d_in[0];
  const float* radiance = (const float*)d_in[1];
  const float* w_rnn = (const float*)d_in[2];
  const float* b_rnn = (const float*)d_in[3];
  const float* w_k1  = (const float*)d_in[4];
  const float* b_k1  = (const float*)d_in[5];
  const float* w_k2  = (const float*)d_in[6];
  const float* b_k2  = (const float*)d_in[7];
  const float* w_k3  = (const float*)d_in[8];
  const float* b_k3  = (const float*)d_in[9];
  float* out = (float*)d_out;

  char* ws = (char*)d_ws;
  size_t off = 0;
  auto alloc = [&](size_t bytes)->char*{
    char* p = ws + off;
    off = (off + bytes + 255) & ~(size_t)255;
    return p;
  };
  const size_t WSLACK = 49152;   // depth-3 pipeline tail over-read slack
  _Float16* wp_rnn   = (_Float16*)alloc((size_t)9*128*160*2 + WSLACK);
  _Float16* wp_k1    = (_Float16*)alloc((size_t)9*128*160*2 + WSLACK);
  _Float16* wp_k2    = (_Float16*)alloc((size_t)9*128*128*2 + WSLACK);
  _Float16* wp_k3    = (_Float16*)alloc((size_t)9*512*128*2 + WSLACK);
  float*    bias_k3p = (float*)   alloc((size_t)512*4);
  // per-batch strides (elements)
  const unsigned RB = 194u*194u*160u;            // rnn_in
  const unsigned KB = (192u*192u+448u)*160u;     // k1_in
  const unsigned K2B = (190u*190u+444u)*128u;    // k2_in
  const unsigned K3B = (194u*188u+256u)*128u;    // k3_in (+slack)
  const unsigned KOB = 441u*34596u;              // k3_out
  _Float16* rnn_in = (_Float16*)alloc((size_t)2*RB*2);
  _Float16* k1_in  = (_Float16*)alloc((size_t)2*KB*2);
  _Float16* k2_in  = (_Float16*)alloc((size_t)2*K2B*2);
  _Float16* k3_in  = (_Float16*)alloc((size_t)2*K3B*2);
  _Float16* k3_out = (_Float16*)alloc((size_t)2*KOB*2);
  float*    accz   = (float*)   alloc((size_t)236678*4);
  if (off > ws_size) return;  // workspace too small -> fail loudly (no OOB writes)

  float*    unnorm = accz;                 // [2][3][172][172]
  float*    sumw   = accz + 177504;        // [2][172][172]
  float*    st     = accz + 236672;        // [2][{M,scale}]
  unsigned* slot   = (unsigned*)(accz + 236676);  // [2]

  // weight prepack (pure function of inputs; runs every call)
  pack_w<<<(9*128*160+255)/256, 256, 0, stream>>>(w_rnn, wp_rnn, 128, 144, 128, 160);
  pack_w<<<(9*128*160+255)/256, 256, 0, stream>>>(w_k1,  wp_k1,  128, 144, 128, 160);
  pack_w<<<(9*128*128+255)/256, 256, 0, stream>>>(w_k2,  wp_k2,  128, 128, 128, 128);
  pack_w<<<(9*512*128+255)/256, 256, 0, stream>>>(w_k3,  wp_k3,  441, 128, 512, 128);
  pack_bias<<<2, 256, 0, stream>>>(b_k3, bias_k3p, 441, 512);

  // zero rnn halo+state (both batches) and accumulators
  zero_u32<<<2048, 256, 0, stream>>>((unsigned*)rnn_in, (int)(2*RB/2));
  zero_u32<<<925,  256, 0, stream>>>((unsigned*)accz, 236678);

  for (int s = 0; s < 8; ++s){
    const float* f   = features + (size_t)s*16*36864;   // batch stride 8*16*36864
    const float* rad = radiance + (size_t)s*3*36864;    // batch stride 8*3*36864
    pack_feat<<<dim3(144,2), 256, 0, stream>>>(f, rnn_in, k1_in, s > 0 ? 1 : 0,
                                               8u*16u*36864u, RB, KB);
    // rnn: 144(160)->128 SAME via zero halo, lrelu; -> k1_in ch0..127
    conv3<160,true ,false><<<dim3(6,48,2), 128, 0, stream>>>(
        rnn_in, 194, RB, wp_rnn, 128, b_rnn, k1_in, 192, 160, KB,
        nullptr, 192, 192, 0, 0);
    // k1: 144(160)->128 VALID, lrelu; -> k2_in (190x190)
    conv3<160,true ,false><<<dim3(6,48,2), 128, 0, stream>>>(
        k1_in, 192, KB, wp_k1, 128, b_k1, k2_in, 190, 128, K2B,
        nullptr, 190, 190, 0, 0);
    // k2: 128->128 VALID, lrelu; -> k3_in (188x188)
    conv3<128,true ,false><<<dim3(6,47,2), 128, 0, stream>>>(
        k2_in, 190, K2B, wp_k2, 128, b_k2, k3_in, 188, 128, K3B,
        nullptr, 188, 188, 0, 0);
    // k3: 128->441(512 pad, 4 slices) VALID, no relu; -> fp16 planes + atomic max
    conv3<128,false,true ><<<dim3(6,47,8), 128, 0, stream>>>(
        k3_in, 188, K3B, wp_k3, 512, bias_k3p, k3_out, 0, 0, KOB,
        slot, 186, 186, 3, 2);
    update_max<<<1, 64, 0, stream>>>(st, slot, s);
    apply_acc<<<dim3(3,43,2), 256, 0, stream>>>(k3_out, rad, st, unnorm, sumw);
  }
  finalize_out<<<dim3(347,2), 256, 0, stream>>>(unnorm, sumw, out);
}